// Round 1
// baseline (110.024 us; speedup 1.0000x reference)
//
#include <hip/hip_runtime.h>
#include <math.h>

#define BATCH 512
#define DIN   5120
#define DST   16
#define RK    160
#define NJ    192   // 160 dt_rank + 16 B + 16 C

// ---------------------------------------------------------------------------
// Kernel 1: P[j,b] = sum_d W[j,d] * x[b,d]   (j<160: W_dt_rank, 160..175: W_B,
// 176..191: W_C).  Split-K with f32 atomicAdd into workspace.
// grid: (3 j-tiles of 64, 8 b-tiles of 64, 16 k-slices of 320), block 256.
// ---------------------------------------------------------------------------
__global__ __launch_bounds__(256) void k_proj(
    const float* __restrict__ x, const float* __restrict__ Wdtr,
    const float* __restrict__ WB, const float* __restrict__ WC,
    float* __restrict__ o_dtr, float* __restrict__ o_B, float* __restrict__ o_C)
{
  const int t  = threadIdx.x;
  const int j0 = blockIdx.x * 64;
  const int b0 = blockIdx.y * 64;
  const int k_start = blockIdx.z * 320;

  __shared__ float sW[16][68];   // [k][j], padded
  __shared__ float sX[16][68];   // [k][b]

  const int tj = t & 15, tb = t >> 4;       // compute mapping: 4 j x 4 b
  const int srow = t >> 2, sq = t & 3;      // staging mapping: row, k-quad

  // global row pointer for the W side (row is fixed per thread)
  const int j = j0 + srow;
  const float* wrow;
  if (j < RK)            wrow = Wdtr + (size_t)j * DIN;
  else if (j < RK + DST) wrow = WB   + (size_t)(j - RK) * DIN;
  else                   wrow = WC   + (size_t)(j - RK - DST) * DIN;
  const float* xrow = x + (size_t)(b0 + srow) * DIN;

  float acc[4][4] = {};

  for (int kc = 0; kc < 20; ++kc) {
    const int k = k_start + kc * 16 + sq * 4;
    const float4 wv = *(const float4*)(wrow + k);
    const float4 xv = *(const float4*)(xrow + k);
    __syncthreads();   // protect LDS from previous iteration's readers
    sW[sq*4+0][srow] = wv.x; sW[sq*4+1][srow] = wv.y;
    sW[sq*4+2][srow] = wv.z; sW[sq*4+3][srow] = wv.w;
    sX[sq*4+0][srow] = xv.x; sX[sq*4+1][srow] = xv.y;
    sX[sq*4+2][srow] = xv.z; sX[sq*4+3][srow] = xv.w;
    __syncthreads();
#pragma unroll
    for (int kk = 0; kk < 16; ++kk) {
      const float4 wf = *(const float4*)&sW[kk][tj*4];
      const float4 xf = *(const float4*)&sX[kk][tb*4];
      const float w[4] = {wf.x, wf.y, wf.z, wf.w};
      const float xr[4] = {xf.x, xf.y, xf.z, xf.w};
#pragma unroll
      for (int a = 0; a < 4; ++a)
#pragma unroll
        for (int c = 0; c < 4; ++c)
          acc[a][c] = fmaf(w[a], xr[c], acc[a][c]);
    }
  }

#pragma unroll
  for (int a = 0; a < 4; ++a) {
    const int jj = j0 + tj * 4 + a;
#pragma unroll
    for (int c = 0; c < 4; ++c) {
      const int bb = b0 + tb * 4 + c;
      const float v = acc[a][c];
      if (jj < RK)            atomicAdd(&o_dtr[(size_t)bb * RK + jj], v);
      else if (jj < RK + DST) atomicAdd(&o_B[(size_t)bb * DST + (jj - RK)], v);
      else                    atomicAdd(&o_C[(size_t)bb * DST + (jj - RK - DST)], v);
    }
  }
}

// ---------------------------------------------------------------------------
// Kernel 2: dt = softplus(dtr @ W_dt^T + b_dt)   (GEMM, K=160, LDS-staged)
// then fused SSM update:
//   y[b,d] = sum_s (exp(A[d,s]*dt)*h[b,d,s] + dt*Bc[b,s]*x[b,d]) * Cc[b,s]
//            + D[d]*x[b,d]
// grid: (80 d-tiles of 64, 8 b-tiles of 64), block 256, 4x4 register tile.
// ---------------------------------------------------------------------------
__global__ __launch_bounds__(256) void k_ssm(
    const float* __restrict__ dtr, const float* __restrict__ Bc,
    const float* __restrict__ Cc,  const float* __restrict__ Wdt,
    const float* __restrict__ bdt, const float* __restrict__ A,
    const float* __restrict__ Dp,  const float* __restrict__ x,
    const float* __restrict__ h,   float* __restrict__ y)
{
  const int t  = threadIdx.x;
  const int d0 = blockIdx.x * 64;
  const int b0 = blockIdx.y * 64;

  __shared__ float sWT[32][68];   // [r][d]
  __shared__ float sDT[32][68];   // [r][b]
  __shared__ float sB[64][16];
  __shared__ float sC[64][16];

  const int tdl = t & 15, tbl = t >> 4;
  const int srow = t >> 2, sq = t & 3;

  // stage Bc/Cc tiles (64 x 16 each)
  {
    const int r = t >> 2, c = (t & 3) * 4;
    *(float4*)&sB[r][c] = *(const float4*)&Bc[(size_t)(b0 + r) * DST + c];
    *(float4*)&sC[r][c] = *(const float4*)&Cc[(size_t)(b0 + r) * DST + c];
  }

  const float* wrow = Wdt + (size_t)(d0 + srow) * RK;
  const float* drow = dtr + (size_t)(b0 + srow) * RK;

  float acc[4][4] = {};   // [id][ib]

  for (int rc = 0; rc < 5; ++rc) {
    const float4 w0 = *(const float4*)(wrow + rc*32 + sq*4);
    const float4 w1 = *(const float4*)(wrow + rc*32 + 16 + sq*4);
    const float4 a0 = *(const float4*)(drow + rc*32 + sq*4);
    const float4 a1 = *(const float4*)(drow + rc*32 + 16 + sq*4);
    __syncthreads();
    sWT[sq*4+0][srow] = w0.x; sWT[sq*4+1][srow] = w0.y;
    sWT[sq*4+2][srow] = w0.z; sWT[sq*4+3][srow] = w0.w;
    sWT[sq*4+16][srow] = w1.x; sWT[sq*4+17][srow] = w1.y;
    sWT[sq*4+18][srow] = w1.z; sWT[sq*4+19][srow] = w1.w;
    sDT[sq*4+0][srow] = a0.x; sDT[sq*4+1][srow] = a0.y;
    sDT[sq*4+2][srow] = a0.z; sDT[sq*4+3][srow] = a0.w;
    sDT[sq*4+16][srow] = a1.x; sDT[sq*4+17][srow] = a1.y;
    sDT[sq*4+18][srow] = a1.z; sDT[sq*4+19][srow] = a1.w;
    __syncthreads();
#pragma unroll
    for (int kk = 0; kk < 32; ++kk) {
      const float4 wf = *(const float4*)&sWT[kk][tdl*4];
      const float4 df = *(const float4*)&sDT[kk][tbl*4];
      const float w[4] = {wf.x, wf.y, wf.z, wf.w};
      const float dd[4] = {df.x, df.y, df.z, df.w};
#pragma unroll
      for (int a = 0; a < 4; ++a)
#pragma unroll
        for (int c = 0; c < 4; ++c)
          acc[a][c] = fmaf(w[a], dd[c], acc[a][c]);
    }
  }

  // ---- phase 2: softplus + state update + y ----
#pragma unroll
  for (int ib = 0; ib < 4; ++ib) {
    const int b = b0 + tbl * 4 + ib;
    const float4 B4a = *(const float4*)&sB[tbl*4+ib][0];
    const float4 B4b = *(const float4*)&sB[tbl*4+ib][4];
    const float4 B4c = *(const float4*)&sB[tbl*4+ib][8];
    const float4 B4d = *(const float4*)&sB[tbl*4+ib][12];
    const float4 C4a = *(const float4*)&sC[tbl*4+ib][0];
    const float4 C4b = *(const float4*)&sC[tbl*4+ib][4];
    const float4 C4c = *(const float4*)&sC[tbl*4+ib][8];
    const float4 C4d = *(const float4*)&sC[tbl*4+ib][12];
    const float Bv[16] = {B4a.x,B4a.y,B4a.z,B4a.w, B4b.x,B4b.y,B4b.z,B4b.w,
                          B4c.x,B4c.y,B4c.z,B4c.w, B4d.x,B4d.y,B4d.z,B4d.w};
    const float Cv[16] = {C4a.x,C4a.y,C4a.z,C4a.w, C4b.x,C4b.y,C4b.z,C4b.w,
                          C4c.x,C4c.y,C4c.z,C4c.w, C4d.x,C4d.y,C4d.z,C4d.w};
#pragma unroll
    for (int id = 0; id < 4; ++id) {
      const int d = d0 + tdl * 4 + id;
      const float pre = acc[id][ib] + bdt[d];
      const float dt = (pre > 20.f) ? pre : log1pf(__expf(pre));
      const float xv = x[(size_t)b * DIN + d];
      float yv = Dp[d] * xv;
      const float* hp = h + ((size_t)b * DIN + d) * DST;
      const float* Ap = A + (size_t)d * DST;
#pragma unroll
      for (int s4 = 0; s4 < 4; ++s4) {
        const float4 h4 = *(const float4*)(hp + s4 * 4);
        const float4 A4 = *(const float4*)(Ap + s4 * 4);
        const float hv[4] = {h4.x, h4.y, h4.z, h4.w};
        const float Av[4] = {A4.x, A4.y, A4.z, A4.w};
#pragma unroll
        for (int s = 0; s < 4; ++s) {
          const float dA = __expf(Av[s] * dt);
          const float hn = dA * hv[s] + dt * Bv[s4*4+s] * xv;
          yv = fmaf(hn, Cv[s4*4+s], yv);
        }
      }
      y[(size_t)b * DIN + d] = yv;
    }
  }
}

extern "C" void kernel_launch(void* const* d_in, const int* in_sizes, int n_in,
                              void* d_out, int out_size, void* d_ws, size_t ws_size,
                              hipStream_t stream) {
  const float* x    = (const float*)d_in[0];
  const float* Wdtr = (const float*)d_in[1];
  const float* Wdt  = (const float*)d_in[2];
  const float* bdt  = (const float*)d_in[3];
  const float* WB   = (const float*)d_in[4];
  const float* WC   = (const float*)d_in[5];
  const float* A    = (const float*)d_in[6];
  const float* Dp   = (const float*)d_in[7];
  const float* h    = (const float*)d_in[8];
  float* y = (float*)d_out;

  float* ws_dtr = (float*)d_ws;                  // [512][160]
  float* ws_B   = ws_dtr + (size_t)BATCH * RK;   // [512][16]
  float* ws_C   = ws_B   + (size_t)BATCH * DST;  // [512][16]

  hipMemsetAsync(d_ws, 0, (size_t)BATCH * NJ * sizeof(float), stream);

  k_proj<<<dim3(3, 8, 16), 256, 0, stream>>>(x, Wdtr, WB, WC, ws_dtr, ws_B, ws_C);
  k_ssm<<<dim3(80, 8), 256, 0, stream>>>(ws_dtr, ws_B, ws_C, Wdt, bdt, A, Dp, x, h, y);
}